// Round 1
// baseline (154.644 us; speedup 1.0000x reference)
//
#include <hip/hip_runtime.h>
#include <hip/hip_bf16.h>
#include <stdint.h>

#define K_DIM 4096
#define N_DIM 11008
#define M_DIM 512
#define PK_ROW (N_DIM / 2)   // 5504 int32 code-bytes per k-row
#define SC_ROW (N_DIM / 64)  // 172 scale blocks per k-row
#define BM 128
#define BN 128
#define BK 64
#define LDS_STRIDE 72        // 64 bf16 + 8 pad -> 144B rows, 2-way-free b128 reads

typedef __attribute__((ext_vector_type(8))) short bf16x8;
typedef __attribute__((ext_vector_type(4))) float f32x4;
typedef __attribute__((ext_vector_type(4))) int i32x4;

__constant__ float NF4[16] = {
    -1.0f, -0.6961928009986877f, -0.5250730514526367f, -0.39491748809814453f,
    -0.28444138169288635f, -0.18477343022823334f, -0.09105003625154495f, 0.0f,
    0.07958029955625534f, 0.16093020141124725f, 0.24611230194568634f,
    0.33791524171829224f, 0.44070982933044434f, 0.5626170039176941f,
    0.7229568362236023f, 1.0f};

__device__ __forceinline__ unsigned f2bf(float v) {
  __hip_bfloat16 h = __float2bfloat16(v);
  union { __hip_bfloat16 h; unsigned short u; } cv;
  cv.h = h;
  return (unsigned)cv.u;
}

__global__ __launch_bounds__(256) void nf4_gemm(
    const float* __restrict__ x, const int* __restrict__ packed,
    const float* __restrict__ scales, const float* __restrict__ bias,
    float* __restrict__ out) {
  __shared__ unsigned short Alds[BM * LDS_STRIDE];  // x tile, bf16, [m][k]
  __shared__ unsigned short Blds[BN * LDS_STRIDE];  // W tile, bf16, [n][k]
  __shared__ float2 Lut[256];                       // byte -> (hi,lo) nf4 vals

  const int t = threadIdx.x;

  // XCD-aware swizzle: 344 blocks = 8 * 43, bijective
  const int bid = blockIdx.x;
  const int swz = (bid & 7) * 43 + (bid >> 3);
  const int m_tile = (swz / 86) * BM;  // 4 m-tiles
  const int n_tile = (swz % 86) * BN;  // 86 n-tiles

  Lut[t] = make_float2(NF4[(t >> 4) & 15], NF4[t & 15]);

  const int lane = t & 63;
  const int wid = t >> 6;
  const int wm = (wid >> 1) * 64;  // wave's m-offset in tile
  const int wn = (wid & 1) * 64;   // wave's n-offset in tile
  const int l15 = lane & 15;
  const int l4 = lane >> 4;

  f32x4 acc[4][4];
#pragma unroll
  for (int i = 0; i < 4; ++i)
#pragma unroll
    for (int j = 0; j < 4; ++j) acc[i][j] = (f32x4){0.f, 0.f, 0.f, 0.f};

  // B-staging mapping: thread owns 8 n-cols x 4 k-rows; diagonal k-rotation
  // spreads LDS write banks (else 8-row stride aliases to one bank).
  const int mlane = t & 15;
  const int n_sub = mlane * 8;
  const int k_sub = 4 * (((t >> 4) + mlane) & 15);
  // A-staging mapping: thread covers float4-granule c4 of rows r0+16i
  const int c4 = t & 15;
  const int r0 = t >> 4;

  for (int k0 = 0; k0 < K_DIM; k0 += BK) {
    __syncthreads();  // also covers Lut init before first stage

    // ---- stage A: x fp32 -> bf16 into Alds[m][k] ----
#pragma unroll
    for (int i = 0; i < 8; ++i) {
      const int row = r0 + 16 * i;
      f32x4 xv = *(const f32x4*)(x + (size_t)(m_tile + row) * K_DIM + k0 + c4 * 4);
      uint2 d;
      d.x = f2bf(xv[0]) | (f2bf(xv[1]) << 16);
      d.y = f2bf(xv[2]) | (f2bf(xv[3]) << 16);
      *(uint2*)(&Alds[row * LDS_STRIDE + c4 * 4]) = d;
    }

    // ---- stage B: dequant NF4 -> bf16 into Blds[n][k] (transposed) ----
    {
      const int* pk = packed + (size_t)(k0 + k_sub) * PK_ROW + ((n_tile + n_sub) >> 1);
      i32x4 w[4];
      float s[4];
#pragma unroll
      for (int kk = 0; kk < 4; ++kk) {
        w[kk] = *(const i32x4*)(pk + (size_t)kk * PK_ROW);
        s[kk] = scales[(size_t)(k0 + k_sub + kk) * SC_ROW + ((n_tile + n_sub) >> 6)];
      }
      float v[4][8];
#pragma unroll
      for (int kk = 0; kk < 4; ++kk) {
#pragma unroll
        for (int e = 0; e < 4; ++e) {
          const int b = w[kk][e] & 0xFF;
          const float2 p = Lut[b];
          v[kk][2 * e] = p.x * s[kk];      // even n  -> high nibble
          v[kk][2 * e + 1] = p.y * s[kk];  // odd n   -> low nibble
        }
      }
#pragma unroll
      for (int j = 0; j < 8; ++j) {
        uint2 d;
        d.x = f2bf(v[0][j]) | (f2bf(v[1][j]) << 16);  // k, k+1
        d.y = f2bf(v[2][j]) | (f2bf(v[3][j]) << 16);  // k+2, k+3
        *(uint2*)(&Blds[(n_sub + j) * LDS_STRIDE + k_sub]) = d;
      }
    }

    __syncthreads();

    // ---- compute: 2 k-steps of 32, 16 MFMA each ----
#pragma unroll
    for (int ks = 0; ks < 2; ++ks) {
      bf16x8 af[4], bf[4];
#pragma unroll
      for (int fm = 0; fm < 4; ++fm)
        af[fm] = *(const bf16x8*)(&Alds[(wm + fm * 16 + l15) * LDS_STRIDE + ks * 32 + l4 * 8]);
#pragma unroll
      for (int fn = 0; fn < 4; ++fn)
        bf[fn] = *(const bf16x8*)(&Blds[(wn + fn * 16 + l15) * LDS_STRIDE + ks * 32 + l4 * 8]);
#pragma unroll
      for (int fm = 0; fm < 4; ++fm)
#pragma unroll
        for (int fn = 0; fn < 4; ++fn)
          acc[fm][fn] = __builtin_amdgcn_mfma_f32_16x16x32_bf16(af[fm], bf[fn], acc[fm][fn], 0, 0, 0);
    }
  }

  // ---- epilogue: C[m][n] = acc + bias; D layout col=l15, row=4*l4+r ----
#pragma unroll
  for (int fn = 0; fn < 4; ++fn) {
    const float bi = bias[n_tile + wn + fn * 16 + l15];
#pragma unroll
    for (int fm = 0; fm < 4; ++fm) {
#pragma unroll
      for (int r = 0; r < 4; ++r) {
        const int gr = m_tile + wm + fm * 16 + l4 * 4 + r;
        out[(size_t)gr * N_DIM + n_tile + wn + fn * 16 + l15] = acc[fm][fn][r] + bi;
      }
    }
  }
}

extern "C" void kernel_launch(void* const* d_in, const int* in_sizes, int n_in,
                              void* d_out, int out_size, void* d_ws, size_t ws_size,
                              hipStream_t stream) {
  const float* x = (const float*)d_in[0];
  const int* packed = (const int*)d_in[1];
  const float* scales = (const float*)d_in[2];
  const float* bias = (const float*)d_in[3];
  float* out = (float*)d_out;

  dim3 grid(344);  // 4 m-tiles * 86 n-tiles
  dim3 block(256);
  nf4_gemm<<<grid, block, 0, stream>>>(x, packed, scales, bias, out);
}